// Round 1
// baseline (80.597 us; speedup 1.0000x reference)
//
#include <hip/hip_runtime.h>
#include <stdint.h>

typedef __bf16 bf16;
typedef __bf16 bf16x8 __attribute__((ext_vector_type(8)));
typedef float f32x4 __attribute__((ext_vector_type(4)));

struct alignas(8) U16x4 { uint16_t v[4]; };

__device__ __forceinline__ f32x4 mfma16(bf16x8 a, bf16x8 b, f32x4 c) {
    return __builtin_amdgcn_mfma_f32_16x16x32_bf16(a, b, c, 0, 0, 0);
}

__device__ __forceinline__ void gload_lds16(const void* g, void* l) {
    __builtin_amdgcn_global_load_lds(
        (const __attribute__((address_space(1))) uint32_t*)g,
        (__attribute__((address_space(3))) uint32_t*)l, 16, 0, 0);
}

__device__ __forceinline__ uint16_t bf_bits(bf16 v) {
    return __builtin_bit_cast(uint16_t, v);
}

// ---------------------------------------------------------------------------
// Projection kernel: out = x @ W + b for q,k,v.  x:[16384,512] f32, W:[512,64]
// Tile: BM=128 rows x N=64, K staged in 8 tiles of 64. 4 waves, each 32 rows.
// q,k stored row-major bf16 [16384][64]; v stored transposed [8][64][2048].
// ---------------------------------------------------------------------------
__global__ __launch_bounds__(256, 2)
void proj_kernel(const float* __restrict__ xq, const float* __restrict__ xk,
                 const float* __restrict__ xv,
                 const float* __restrict__ Wq, const float* __restrict__ bq,
                 const float* __restrict__ Wk, const float* __restrict__ bk,
                 const float* __restrict__ Wv, const float* __restrict__ bv,
                 uint16_t* __restrict__ q_ws, uint16_t* __restrict__ k_ws,
                 uint16_t* __restrict__ vt_ws)
{
    const int p = blockIdx.y;
    const float* x    = (p == 0) ? xq : (p == 1) ? xk : xv;
    const float* W    = (p == 0) ? Wq : (p == 1) ? Wk : Wv;
    const float* bias = (p == 0) ? bq : (p == 1) ? bk : bv;

    const int m0 = blockIdx.x * 128;
    const int t  = threadIdx.x;
    const int l  = t & 63;
    const int w  = t >> 6;

    __shared__ __align__(16) uint16_t sX[2][128 * 64];  // [row][k] bf16, swizzled
    __shared__ __align__(16) uint16_t sW[2][64 * 64];   // [n][k]  bf16, swizzled

    f32x4 acc[2][4];
    const f32x4 zero = {0.f, 0.f, 0.f, 0.f};
    #pragma unroll
    for (int mi = 0; mi < 2; mi++)
        #pragma unroll
        for (int f = 0; f < 4; f++) acc[mi][f] = zero;

    auto stageX = [&](int kt, int buf) {
        const int r  = t & 127;
        const int ch = t >> 7;
        const float* src = x + (size_t)(m0 + r) * 512 + kt * 64;
        #pragma unroll
        for (int pass = 0; pass < 4; pass++) {
            const int c0 = (ch * 4 + pass) * 8;
            float4 v0 = *(const float4*)(src + c0);
            float4 v1 = *(const float4*)(src + c0 + 4);
            bf16x8 v;
            v[0] = (bf16)v0.x; v[1] = (bf16)v0.y; v[2] = (bf16)v0.z; v[3] = (bf16)v0.w;
            v[4] = (bf16)v1.x; v[5] = (bf16)v1.y; v[6] = (bf16)v1.z; v[7] = (bf16)v1.w;
            const int byte = r * 128 + ((c0 * 2) ^ ((r & 7) << 4));
            *(bf16x8*)((char*)sX[buf] + byte) = v;
        }
    };

    auto stageW = [&](int kt, int buf) {
        const float* src = W + (size_t)(kt * 64 + l) * 64;
        #pragma unroll
        for (int pass = 0; pass < 2; pass++) {
            const int n0 = (w * 2 + pass) * 8;
            float4 v0 = *(const float4*)(src + n0);
            float4 v1 = *(const float4*)(src + n0 + 4);
            float vv[8] = {v0.x, v0.y, v0.z, v0.w, v1.x, v1.y, v1.z, v1.w};
            #pragma unroll
            for (int j = 0; j < 8; j++) {
                const int n = n0 + j;
                const int byte = n * 128 + ((l * 2) ^ ((n & 7) << 4));
                *(bf16*)((char*)sW[buf] + byte) = (bf16)vv[j];
            }
        }
    };

    auto compute = [&](int buf) {
        #pragma unroll
        for (int ks = 0; ks < 2; ks++) {
            const int kb = (l >> 4) * 16 + ks * 64;  // byte offset along k
            bf16x8 a[2], bfr[4];
            #pragma unroll
            for (int mi = 0; mi < 2; mi++) {
                const int r = w * 32 + mi * 16 + (l & 15);
                a[mi] = *(const bf16x8*)((const char*)sX[buf] + r * 128 + (kb ^ ((r & 7) << 4)));
            }
            #pragma unroll
            for (int f = 0; f < 4; f++) {
                const int n = (l & 15) + 16 * f;
                bfr[f] = *(const bf16x8*)((const char*)sW[buf] + n * 128 + (kb ^ ((n & 7) << 4)));
            }
            #pragma unroll
            for (int mi = 0; mi < 2; mi++)
                #pragma unroll
                for (int f = 0; f < 4; f++)
                    acc[mi][f] = mfma16(a[mi], bfr[f], acc[mi][f]);
        }
    };

    stageX(0, 0); stageW(0, 0);
    __syncthreads();
    for (int kt = 0; kt < 8; kt++) {
        const int buf = kt & 1;
        if (kt < 7) { stageX(kt + 1, buf ^ 1); stageW(kt + 1, buf ^ 1); }
        compute(buf);
        __syncthreads();
    }

    float bv4[4];
    #pragma unroll
    for (int f = 0; f < 4; f++) bv4[f] = bias[16 * f + (l & 15)];

    if (p < 2) {
        uint16_t* outp = (p == 0) ? q_ws : k_ws;
        #pragma unroll
        for (int mi = 0; mi < 2; mi++)
            #pragma unroll
            for (int f = 0; f < 4; f++)
                #pragma unroll
                for (int r = 0; r < 4; r++) {
                    const int row = m0 + w * 32 + mi * 16 + (l >> 4) * 4 + r;
                    const int col = 16 * f + (l & 15);
                    outp[(size_t)row * 64 + col] = bf_bits((bf16)(acc[mi][f][r] + bv4[f]));
                }
    } else {
        #pragma unroll
        for (int mi = 0; mi < 2; mi++)
            #pragma unroll
            for (int f = 0; f < 4; f++) {
                const int row0 = m0 + w * 32 + mi * 16 + (l >> 4) * 4;
                const int col  = 16 * f + (l & 15);
                const int bb = row0 >> 11;
                const int s0 = row0 & 2047;
                U16x4 pk;
                #pragma unroll
                for (int r = 0; r < 4; r++)
                    pk.v[r] = bf_bits((bf16)(acc[mi][f][r] + bv4[f]));
                *(U16x4*)(vt_ws + ((size_t)bb * 64 + col) * 2048 + s0) = pk;
            }
    }
}

// ---------------------------------------------------------------------------
// Flash attention: per block, one batch b and one 64-row q tile. 4 waves,
// each wave owns 16 q rows. KV tiles of 64, double-buffered via
// global_load_lds with pre-swizzled global source (LDS stays linear-dest).
// ---------------------------------------------------------------------------
__global__ __launch_bounds__(256, 2)
void attn_kernel(const uint16_t* __restrict__ q_ws, const uint16_t* __restrict__ k_ws,
                 const uint16_t* __restrict__ vt_ws, float* __restrict__ out)
{
    const int qt = blockIdx.x, b = blockIdx.y;
    const int t = threadIdx.x, l = t & 63, w = t >> 6;
    const int q0 = qt * 64;

    __shared__ __align__(16) uint16_t sK[2][64 * 64];  // [s][d] swizzled
    __shared__ __align__(16) uint16_t sV[2][64 * 64];  // [dv][s] swizzled
    __shared__ __align__(16) uint16_t sP[4][16 * 64];  // per-wave P, swizzled

    const uint16_t* qp = q_ws + ((size_t)(b * 2048 + q0)) * 64;
    const uint16_t* kp = k_ws + (size_t)b * 2048 * 64;
    const uint16_t* vp = vt_ws + (size_t)b * 64 * 2048;

    // Q fragments (scaled by 1/sqrt(64) = 0.125, exact in bf16)
    bf16x8 aq[2];
    #pragma unroll
    for (int ks = 0; ks < 2; ks++) {
        const uint16_t* src = qp + (size_t)(w * 16 + (l & 15)) * 64 + (l >> 4) * 8 + ks * 32;
        bf16x8 raw = *(const bf16x8*)src;
        #pragma unroll
        for (int j = 0; j < 8; j++) aq[ks][j] = (bf16)((float)raw[j] * 0.125f);
    }

    const f32x4 zero = {0.f, 0.f, 0.f, 0.f};
    f32x4 acco[4];
    #pragma unroll
    for (int f = 0; f < 4; f++) acco[f] = zero;
    float m_r[4], l_r[4];
    #pragma unroll
    for (int r = 0; r < 4; r++) { m_r[r] = -__builtin_inff(); l_r[r] = 0.f; }

    auto stage = [&](int tile, int buf) {
        const int kv0 = tile * 64;
        #pragma unroll
        for (int c = 0; c < 2; c++) {
            const int row  = (w * 2 + c) * 8 + (l >> 3);
            const int slot = (l & 7) ^ (l >> 3);
            gload_lds16(kp + (size_t)(kv0 + row) * 64 + slot * 8,
                        (char*)sK[buf] + (w * 2 + c) * 1024);
            gload_lds16(vp + (size_t)row * 2048 + kv0 + slot * 8,
                        (char*)sV[buf] + (w * 2 + c) * 1024);
        }
    };

    stage(0, 0);
    __syncthreads();

    for (int tile = 0; tile < 32; tile++) {
        const int buf = tile & 1;
        if (tile < 31) stage(tile + 1, buf ^ 1);

        // ---- scores: S = (Q/8) K^T  (C layout: row=(l>>4)*4+r, col=(l&15)+16f)
        f32x4 accs[4];
        #pragma unroll
        for (int f = 0; f < 4; f++) accs[f] = zero;
        #pragma unroll
        for (int ks = 0; ks < 2; ks++) {
            const int kb = (l >> 4) * 16 + ks * 64;
            #pragma unroll
            for (int f = 0; f < 4; f++) {
                const int srow = (l & 15) + 16 * f;
                bf16x8 bk = *(const bf16x8*)((const char*)sK[buf] + srow * 128 + (kb ^ ((srow & 7) << 4)));
                accs[f] = mfma16(aq[ks], bk, accs[f]);
            }
        }

        // ---- online softmax (row reduce across 16-lane groups)
        float mx[4];
        #pragma unroll
        for (int r = 0; r < 4; r++)
            mx[r] = fmaxf(fmaxf(accs[0][r], accs[1][r]), fmaxf(accs[2][r], accs[3][r]));
        #pragma unroll
        for (int off = 1; off < 16; off <<= 1)
            #pragma unroll
            for (int r = 0; r < 4; r++) mx[r] = fmaxf(mx[r], __shfl_xor(mx[r], off));

        float corr[4];
        #pragma unroll
        for (int r = 0; r < 4; r++) {
            const float mnew = fmaxf(m_r[r], mx[r]);
            corr[r] = __expf(m_r[r] - mnew);
            m_r[r] = mnew;
        }
        float rs[4] = {0.f, 0.f, 0.f, 0.f};
        bf16 pb[4][4];
        #pragma unroll
        for (int f = 0; f < 4; f++)
            #pragma unroll
            for (int r = 0; r < 4; r++) {
                const float pv = __expf(accs[f][r] - m_r[r]);
                rs[r] += pv;
                pb[f][r] = (bf16)pv;
            }
        #pragma unroll
        for (int off = 1; off < 16; off <<= 1)
            #pragma unroll
            for (int r = 0; r < 4; r++) rs[r] += __shfl_xor(rs[r], off);
        #pragma unroll
        for (int r = 0; r < 4; r++) l_r[r] = l_r[r] * corr[r] + rs[r];
        #pragma unroll
        for (int f = 0; f < 4; f++)
            #pragma unroll
            for (int r = 0; r < 4; r++) acco[f][r] *= corr[r];

        // ---- P to LDS (C layout -> A layout round trip), per-wave region
        #pragma unroll
        for (int f = 0; f < 4; f++)
            #pragma unroll
            for (int r = 0; r < 4; r++) {
                const int row = (l >> 4) * 4 + r;
                const int col = (l & 15) + 16 * f;
                const int byte = row * 128 + ((col * 2) ^ ((row & 7) << 4));
                *(bf16*)((char*)sP[w] + byte) = pb[f][r];
            }
        asm volatile("s_waitcnt lgkmcnt(0)" ::: "memory");

        // ---- PV
        #pragma unroll
        for (int ks = 0; ks < 2; ks++) {
            const int kb = (l >> 4) * 16 + ks * 64;
            const int prow = l & 15;
            bf16x8 ap = *(const bf16x8*)((const char*)sP[w] + prow * 128 + (kb ^ ((prow & 7) << 4)));
            #pragma unroll
            for (int f = 0; f < 4; f++) {
                const int vrow = (l & 15) + 16 * f;
                bf16x8 bv2 = *(const bf16x8*)((const char*)sV[buf] + vrow * 128 + (kb ^ ((vrow & 7) << 4)));
                acco[f] = mfma16(ap, bv2, acco[f]);
            }
        }
        __syncthreads();
    }

    // ---- epilogue: out[b][q][dv] f32
    #pragma unroll
    for (int f = 0; f < 4; f++)
        #pragma unroll
        for (int r = 0; r < 4; r++) {
            const int qrow = q0 + w * 16 + (l >> 4) * 4 + r;
            const int col  = 16 * f + (l & 15);
            out[((size_t)(b * 2048 + qrow)) * 64 + col] = acco[f][r] / l_r[r];
        }
}

// ---------------------------------------------------------------------------
extern "C" void kernel_launch(void* const* d_in, const int* in_sizes, int n_in,
                              void* d_out, int out_size, void* d_ws, size_t ws_size,
                              hipStream_t stream) {
    const float* xq = (const float*)d_in[0];
    const float* xk = (const float*)d_in[1];
    const float* xv = (const float*)d_in[2];
    const float* Wq = (const float*)d_in[3];
    const float* bq = (const float*)d_in[4];
    const float* Wk = (const float*)d_in[5];
    const float* bk = (const float*)d_in[6];
    const float* Wv = (const float*)d_in[7];
    const float* bv = (const float*)d_in[8];

    uint16_t* q_ws  = (uint16_t*)d_ws;
    uint16_t* k_ws  = q_ws + (size_t)16384 * 64;
    uint16_t* vt_ws = k_ws + (size_t)16384 * 64;
    float* out = (float*)d_out;

    proj_kernel<<<dim3(128, 3), 256, 0, stream>>>(xq, xk, xv, Wq, bq, Wk, bk, Wv, bv,
                                                  q_ws, k_ws, vt_ws);
    attn_kernel<<<dim3(32, 8), 256, 0, stream>>>(q_ws, k_ws, vt_ws, out);
}

// Round 2
// 68.294 us; speedup vs baseline: 1.1801x; 1.1801x over previous
//
#include <hip/hip_runtime.h>
#include <stdint.h>

typedef __bf16 bf16;
typedef __bf16 bf16x8 __attribute__((ext_vector_type(8)));
typedef float f32x4 __attribute__((ext_vector_type(4)));

struct alignas(8) U16x4 { uint16_t v[4]; };

__device__ __forceinline__ f32x4 mfma16(bf16x8 a, bf16x8 b, f32x4 c) {
    return __builtin_amdgcn_mfma_f32_16x16x32_bf16(a, b, c, 0, 0, 0);
}

__device__ __forceinline__ void gload_lds16(const void* g, void* l) {
    __builtin_amdgcn_global_load_lds(
        (const __attribute__((address_space(1))) uint32_t*)g,
        (__attribute__((address_space(3))) uint32_t*)l, 16, 0, 0);
}

__device__ __forceinline__ uint16_t bf_bits(bf16 v) {
    return __builtin_bit_cast(uint16_t, v);
}

// ---------------------------------------------------------------------------
// Projection kernel: out = x @ W + b for q,k,v.  x:[16384,512] f32, W:[512,64]
// Tile: BM=64 rows x N=64, K staged in 8 tiles of 64. 4 waves, each 16 rows.
// q (pre-scaled by 1/8), k row-major bf16 [16384][64]; v transposed [8][64][2048].
// ---------------------------------------------------------------------------
__global__ __launch_bounds__(256, 4)
void proj_kernel(const float* __restrict__ xq, const float* __restrict__ xk,
                 const float* __restrict__ xv,
                 const float* __restrict__ Wq, const float* __restrict__ bq,
                 const float* __restrict__ Wk, const float* __restrict__ bk,
                 const float* __restrict__ Wv, const float* __restrict__ bv,
                 uint16_t* __restrict__ q_ws, uint16_t* __restrict__ k_ws,
                 uint16_t* __restrict__ vt_ws)
{
    const int p = blockIdx.y;
    const float* x    = (p == 0) ? xq : (p == 1) ? xk : xv;
    const float* W    = (p == 0) ? Wq : (p == 1) ? Wk : Wv;
    const float* bias = (p == 0) ? bq : (p == 1) ? bk : bv;

    const int m0 = blockIdx.x * 64;
    const int t  = threadIdx.x;
    const int l  = t & 63;
    const int w  = t >> 6;

    __shared__ __align__(16) uint16_t sX[2][64 * 64];  // [row][k] bf16, swizzled
    __shared__ __align__(16) uint16_t sW[2][64 * 64];  // [n][k]  bf16, swizzled

    f32x4 acc[4];
    const f32x4 zero = {0.f, 0.f, 0.f, 0.f};
    #pragma unroll
    for (int f = 0; f < 4; f++) acc[f] = zero;

    auto stageX = [&](int kt, int buf) {
        const int r  = t & 63;
        const int ch = t >> 6;
        const float* src = x + (size_t)(m0 + r) * 512 + kt * 64;
        #pragma unroll
        for (int pass = 0; pass < 2; pass++) {
            const int c0 = ch * 16 + pass * 8;
            float4 v0 = *(const float4*)(src + c0);
            float4 v1 = *(const float4*)(src + c0 + 4);
            bf16x8 v;
            v[0] = (bf16)v0.x; v[1] = (bf16)v0.y; v[2] = (bf16)v0.z; v[3] = (bf16)v0.w;
            v[4] = (bf16)v1.x; v[5] = (bf16)v1.y; v[6] = (bf16)v1.z; v[7] = (bf16)v1.w;
            const int byte = r * 128 + ((c0 * 2) ^ ((r & 7) << 4));
            *(bf16x8*)((char*)sX[buf] + byte) = v;
        }
    };

    auto stageW = [&](int kt, int buf) {
        const float* src = W + (size_t)(kt * 64 + l) * 64;
        #pragma unroll
        for (int pass = 0; pass < 2; pass++) {
            const int n0 = (w * 2 + pass) * 8;
            float4 v0 = *(const float4*)(src + n0);
            float4 v1 = *(const float4*)(src + n0 + 4);
            float vv[8] = {v0.x, v0.y, v0.z, v0.w, v1.x, v1.y, v1.z, v1.w};
            #pragma unroll
            for (int j = 0; j < 8; j++) {
                const int n = n0 + j;
                const int byte = n * 128 + ((l * 2) ^ ((n & 7) << 4));
                *(bf16*)((char*)sW[buf] + byte) = (bf16)vv[j];
            }
        }
    };

    auto compute = [&](int buf) {
        #pragma unroll
        for (int ks = 0; ks < 2; ks++) {
            const int kb = (l >> 4) * 16 + ks * 64;  // byte offset along k
            const int r = w * 16 + (l & 15);
            bf16x8 a = *(const bf16x8*)((const char*)sX[buf] + r * 128 + (kb ^ ((r & 7) << 4)));
            #pragma unroll
            for (int f = 0; f < 4; f++) {
                const int n = (l & 15) + 16 * f;
                bf16x8 bfr = *(const bf16x8*)((const char*)sW[buf] + n * 128 + (kb ^ ((n & 7) << 4)));
                acc[f] = mfma16(a, bfr, acc[f]);
            }
        }
    };

    stageX(0, 0); stageW(0, 0);
    __syncthreads();
    for (int kt = 0; kt < 8; kt++) {
        const int buf = kt & 1;
        if (kt < 7) { stageX(kt + 1, buf ^ 1); stageW(kt + 1, buf ^ 1); }
        compute(buf);
        __syncthreads();
    }

    float bv4[4];
    #pragma unroll
    for (int f = 0; f < 4; f++) bv4[f] = bias[16 * f + (l & 15)];

    if (p < 2) {
        uint16_t* outp = (p == 0) ? q_ws : k_ws;
        const float scale = (p == 0) ? 0.125f : 1.0f;  // fold 1/sqrt(64) into q
        #pragma unroll
        for (int f = 0; f < 4; f++)
            #pragma unroll
            for (int r = 0; r < 4; r++) {
                const int row = m0 + w * 16 + (l >> 4) * 4 + r;
                const int col = 16 * f + (l & 15);
                outp[(size_t)row * 64 + col] = bf_bits((bf16)((acc[f][r] + bv4[f]) * scale));
            }
    } else {
        #pragma unroll
        for (int f = 0; f < 4; f++) {
            const int row0 = m0 + w * 16 + (l >> 4) * 4;
            const int col  = 16 * f + (l & 15);
            const int bb = row0 >> 11;
            const int s0 = row0 & 2047;
            U16x4 pk;
            #pragma unroll
            for (int r = 0; r < 4; r++)
                pk.v[r] = bf_bits((bf16)(acc[f][r] + bv4[f]));
            *(U16x4*)(vt_ws + ((size_t)bb * 64 + col) * 2048 + s0) = pk;
        }
    }
}

// ---------------------------------------------------------------------------
// Flash attention with KV-split. Each block: one batch b, one 64-row q tile,
// one KV chunk of 2048/NCHUNK positions. 4 waves x 16 q rows. KV tiles of 64,
// double-buffered via global_load_lds with pre-swizzled global source.
// NCHUNK>1: writes unnormalized O_part + (m,l); combine_kernel merges.
// ---------------------------------------------------------------------------
template <int NCHUNK>
__global__ __launch_bounds__(256, 4)
void attn_kernel(const uint16_t* __restrict__ q_ws, const uint16_t* __restrict__ k_ws,
                 const uint16_t* __restrict__ vt_ws, float* __restrict__ out,
                 float* __restrict__ O_part, float* __restrict__ m_arr,
                 float* __restrict__ l_arr)
{
    constexpr int NT = 32 / NCHUNK;  // KV tiles per chunk
    const int qt = blockIdx.x, b = blockIdx.y, c = blockIdx.z;
    const int t = threadIdx.x, l = t & 63, w = t >> 6;
    const int q0 = qt * 64;

    __shared__ __align__(16) uint16_t sK[2][64 * 64];  // [s][d] swizzled
    __shared__ __align__(16) uint16_t sV[2][64 * 64];  // [dv][s] swizzled
    __shared__ __align__(16) uint16_t sP[4][16 * 64];  // per-wave P, swizzled

    const uint16_t* qp = q_ws + ((size_t)(b * 2048 + q0)) * 64;
    const uint16_t* kp = k_ws + (size_t)b * 2048 * 64;
    const uint16_t* vp = vt_ws + (size_t)b * 64 * 2048;

    // Q fragments (already scaled by 1/8 in proj)
    bf16x8 aq[2];
    #pragma unroll
    for (int ks = 0; ks < 2; ks++)
        aq[ks] = *(const bf16x8*)(qp + (size_t)(w * 16 + (l & 15)) * 64 + (l >> 4) * 8 + ks * 32);

    const f32x4 zero = {0.f, 0.f, 0.f, 0.f};
    f32x4 acco[4];
    #pragma unroll
    for (int f = 0; f < 4; f++) acco[f] = zero;
    float m_r[4], l_r[4];
    #pragma unroll
    for (int r = 0; r < 4; r++) { m_r[r] = -__builtin_inff(); l_r[r] = 0.f; }

    auto stage = [&](int tile, int buf) {
        const int kv0 = tile * 64;
        #pragma unroll
        for (int cc = 0; cc < 2; cc++) {
            const int row  = (w * 2 + cc) * 8 + (l >> 3);
            const int slot = (l & 7) ^ (l >> 3);
            gload_lds16(kp + (size_t)(kv0 + row) * 64 + slot * 8,
                        (char*)sK[buf] + (w * 2 + cc) * 1024);
            gload_lds16(vp + (size_t)row * 2048 + kv0 + slot * 8,
                        (char*)sV[buf] + (w * 2 + cc) * 1024);
        }
    };

    stage(c * NT, 0);
    __syncthreads();

    for (int i = 0; i < NT; i++) {
        const int buf = i & 1;
        if (i < NT - 1) stage(c * NT + i + 1, buf ^ 1);

        // ---- scores: S = (Q/8) K^T  (C layout: row=(l>>4)*4+r, col=(l&15)+16f)
        f32x4 accs[4];
        #pragma unroll
        for (int f = 0; f < 4; f++) accs[f] = zero;
        #pragma unroll
        for (int ks = 0; ks < 2; ks++) {
            const int kb = (l >> 4) * 16 + ks * 64;
            #pragma unroll
            for (int f = 0; f < 4; f++) {
                const int srow = (l & 15) + 16 * f;
                bf16x8 bk = *(const bf16x8*)((const char*)sK[buf] + srow * 128 + (kb ^ ((srow & 7) << 4)));
                accs[f] = mfma16(aq[ks], bk, accs[f]);
            }
        }

        // ---- online softmax (row reduce across 16-lane groups)
        float mx[4];
        #pragma unroll
        for (int r = 0; r < 4; r++)
            mx[r] = fmaxf(fmaxf(accs[0][r], accs[1][r]), fmaxf(accs[2][r], accs[3][r]));
        #pragma unroll
        for (int off = 1; off < 16; off <<= 1)
            #pragma unroll
            for (int r = 0; r < 4; r++) mx[r] = fmaxf(mx[r], __shfl_xor(mx[r], off));

        float corr[4];
        #pragma unroll
        for (int r = 0; r < 4; r++) {
            const float mnew = fmaxf(m_r[r], mx[r]);
            corr[r] = __expf(m_r[r] - mnew);
            m_r[r] = mnew;
        }
        float rs[4] = {0.f, 0.f, 0.f, 0.f};
        bf16 pb[4][4];
        #pragma unroll
        for (int f = 0; f < 4; f++)
            #pragma unroll
            for (int r = 0; r < 4; r++) {
                const float pv = __expf(accs[f][r] - m_r[r]);
                rs[r] += pv;
                pb[f][r] = (bf16)pv;
            }
        #pragma unroll
        for (int off = 1; off < 16; off <<= 1)
            #pragma unroll
            for (int r = 0; r < 4; r++) rs[r] += __shfl_xor(rs[r], off);
        #pragma unroll
        for (int r = 0; r < 4; r++) l_r[r] = l_r[r] * corr[r] + rs[r];
        #pragma unroll
        for (int f = 0; f < 4; f++)
            #pragma unroll
            for (int r = 0; r < 4; r++) acco[f][r] *= corr[r];

        // ---- P to LDS (C layout -> A layout round trip), per-wave region
        #pragma unroll
        for (int f = 0; f < 4; f++)
            #pragma unroll
            for (int r = 0; r < 4; r++) {
                const int row = (l >> 4) * 4 + r;
                const int col = (l & 15) + 16 * f;
                const int byte = row * 128 + ((col * 2) ^ ((row & 7) << 4));
                *(bf16*)((char*)sP[w] + byte) = pb[f][r];
            }
        asm volatile("s_waitcnt lgkmcnt(0)" ::: "memory");

        // ---- PV
        #pragma unroll
        for (int ks = 0; ks < 2; ks++) {
            const int kb = (l >> 4) * 16 + ks * 64;
            const int prow = l & 15;
            bf16x8 ap = *(const bf16x8*)((const char*)sP[w] + prow * 128 + (kb ^ ((prow & 7) << 4)));
            #pragma unroll
            for (int f = 0; f < 4; f++) {
                const int vrow = (l & 15) + 16 * f;
                bf16x8 bv2 = *(const bf16x8*)((const char*)sV[buf] + vrow * 128 + (kb ^ ((vrow & 7) << 4)));
                acco[f] = mfma16(ap, bv2, acco[f]);
            }
        }
        __syncthreads();
    }

    if constexpr (NCHUNK == 1) {
        #pragma unroll
        for (int f = 0; f < 4; f++)
            #pragma unroll
            for (int r = 0; r < 4; r++) {
                const int qrow = q0 + w * 16 + (l >> 4) * 4 + r;
                const int col  = 16 * f + (l & 15);
                out[((size_t)(b * 2048 + qrow)) * 64 + col] = acco[f][r] / l_r[r];
            }
    } else {
        #pragma unroll
        for (int f = 0; f < 4; f++)
            #pragma unroll
            for (int r = 0; r < 4; r++) {
                const int qrow = q0 + w * 16 + (l >> 4) * 4 + r;
                const int col  = 16 * f + (l & 15);
                O_part[((size_t)c * 16384 + b * 2048 + qrow) * 64 + col] = acco[f][r];
            }
        if ((l & 15) == 0) {
            #pragma unroll
            for (int r = 0; r < 4; r++) {
                const size_t idx = (size_t)c * 16384 + b * 2048 + q0 + w * 16 + (l >> 4) * 4 + r;
                m_arr[idx] = m_r[r];
                l_arr[idx] = l_r[r];
            }
        }
    }
}

// ---------------------------------------------------------------------------
// Combine: merge NCHUNK=4 partials. Grid (128, 8): bx>>2 = qtile, bx&3 = row
// quarter. Each block covers 16 q-rows x 64 cols.
// ---------------------------------------------------------------------------
__global__ __launch_bounds__(256, 8)
void combine_kernel(const float* __restrict__ O_part, const float* __restrict__ m_arr,
                    const float* __restrict__ l_arr, float* __restrict__ out)
{
    const int b = blockIdx.y;
    const int r0 = (blockIdx.x >> 2) * 64 + (blockIdx.x & 3) * 16;
    const int t = threadIdx.x;
    const int col = t & 63;
    const int rg = t >> 6;

    #pragma unroll
    for (int pass = 0; pass < 4; pass++) {
        const int qrow = r0 + pass * 4 + rg;
        const size_t ridx = (size_t)b * 2048 + qrow;
        float m[4], lv[4];
        #pragma unroll
        for (int c = 0; c < 4; c++) {
            m[c]  = m_arr[(size_t)c * 16384 + ridx];
            lv[c] = l_arr[(size_t)c * 16384 + ridx];
        }
        const float M = fmaxf(fmaxf(m[0], m[1]), fmaxf(m[2], m[3]));
        float L = 0.f, wgt[4];
        #pragma unroll
        for (int c = 0; c < 4; c++) { wgt[c] = __expf(m[c] - M); L += lv[c] * wgt[c]; }
        float acc = 0.f;
        #pragma unroll
        for (int c = 0; c < 4; c++)
            acc += O_part[((size_t)c * 16384 + ridx) * 64 + col] * wgt[c];
        out[ridx * 64 + col] = acc / L;
    }
}

// ---------------------------------------------------------------------------
extern "C" void kernel_launch(void* const* d_in, const int* in_sizes, int n_in,
                              void* d_out, int out_size, void* d_ws, size_t ws_size,
                              hipStream_t stream) {
    const float* xq = (const float*)d_in[0];
    const float* xk = (const float*)d_in[1];
    const float* xv = (const float*)d_in[2];
    const float* Wq = (const float*)d_in[3];
    const float* bq = (const float*)d_in[4];
    const float* Wk = (const float*)d_in[5];
    const float* bk = (const float*)d_in[6];
    const float* Wv = (const float*)d_in[7];
    const float* bv = (const float*)d_in[8];

    uint16_t* q_ws  = (uint16_t*)d_ws;
    uint16_t* k_ws  = q_ws + (size_t)16384 * 64;
    uint16_t* vt_ws = k_ws + (size_t)16384 * 64;
    char*  after_qkv = (char*)(vt_ws + (size_t)16384 * 64);     // 6 MB in
    float* O_part = (float*)after_qkv;                           // 16.78 MB
    float* m_arr  = (float*)(after_qkv + (size_t)4 * 16384 * 64 * 4);
    float* l_arr  = m_arr + (size_t)4 * 16384;
    float* out = (float*)d_out;

    const size_t need = (size_t)3 * 16384 * 64 * 2            // q,k,vt bf16
                      + (size_t)4 * 16384 * 64 * 4            // O_part
                      + (size_t)2 * 4 * 16384 * 4;            // m,l

    proj_kernel<<<dim3(256, 3), 256, 0, stream>>>(xq, xk, xv, Wq, bq, Wk, bk, Wv, bv,
                                                  q_ws, k_ws, vt_ws);
    if (ws_size >= need) {
        attn_kernel<4><<<dim3(32, 8, 4), 256, 0, stream>>>(q_ws, k_ws, vt_ws, out,
                                                           O_part, m_arr, l_arr);
        combine_kernel<<<dim3(128, 8), 256, 0, stream>>>(O_part, m_arr, l_arr, out);
    } else {
        attn_kernel<1><<<dim3(32, 8, 1), 256, 0, stream>>>(q_ws, k_ws, vt_ws, out,
                                                           nullptr, nullptr, nullptr);
    }
}